// Round 3
// baseline (408.130 us; speedup 1.0000x reference)
//
#include <hip/hip_runtime.h>
#include <hip/hip_bf16.h>
#include <cmath>

// ---------------------------------------------------------------------------
// BeliefTransformerBlock: LN1 -> QKV -> masked attention -> LN2 -> FC+GELU -> proj
// B=32, N=1024, D=512.
//
// R3: dense GEMMs (QKV/FC/proj, K=512) on gemm256p: the m201-style 8-phase
// schedule in plain HIP. 256^2 tile, 8 waves (2Mx4N, wave-tile 128x64),
// BK=64, 2 LDS buffers (128 KiB). Per K-tile, 4 phases; each phase:
//   { ds_read one frag quadrant | 2x global_load_lds staging } -> barrier
//   -> lgkmcnt(0) -> setprio(1) 16 MFMA setprio(0) -> barrier
// vmcnt(6) ONCE per K-tile (at P4), never a drain-to-0 in the loop.
// Staging targets only phase-dead LDS regions:
//   P1 stages A-hi(t+1)  (opposite buffer)
//   P2 stages A-lo(t+2)  (same buffer; A-lo dead after P1)
//   P3 stages B-lo(t+2)  (B fully dead after P2)
//   P4 stages B-hi(t+2)
// Ledger: 6 outstanding after each P4 vmcnt; oldest-8 drained at P4(t) are
// exactly tile t+1's 8 loads. Tail clamps restage an existing tile
// (identical bytes -> benign).
//
// Attention GEMMs (masked) stay on the 128^2 gemm_bt.
//
// d_ws layout (floor 100 MiB):
//   0  wqkvT/wfcT/wprojT (4 MiB)
//   4  qk [b][n][1024] q|k (64 MiB)   -> after scores: y @4 (32), ln2o @36 (32)
//   68 vT [b][d][n] (32 MiB)          -> after attnV: gelub @68 (32)
// d_out (64 MiB): h/scoresAll scratch, finally fp32 out.
// ---------------------------------------------------------------------------

using f16 = _Float16;
typedef _Float16 f16x8 __attribute__((ext_vector_type(8)));
typedef _Float16 f16x4 __attribute__((ext_vector_type(4)));
typedef _Float16 f16x2 __attribute__((ext_vector_type(2)));
typedef float f32x4 __attribute__((ext_vector_type(4)));

#define NB 32
#define NN 1024
#define ND 512

#define GLOAD_LDS16(g, l)                                                     \
    __builtin_amdgcn_global_load_lds(                                         \
        (const __attribute__((address_space(1))) void*)(g),                   \
        (__attribute__((address_space(3))) void*)(l), 16, 0, 0)

// ---------------------------------------------------------------------------
// All three weights cast + transposed in ONE launch. z: 0=qkv 1=fc 2=proj.
// ---------------------------------------------------------------------------
__global__ void transpose_cast_all(const float* __restrict__ wqkv, f16* __restrict__ wqkvT,
                                   const float* __restrict__ wfc, f16* __restrict__ wfcT,
                                   const float* __restrict__ wproj, f16* __restrict__ wprojT) {
    const int z = blockIdx.z;
    const float* w = (z == 0) ? wqkv : (z == 1) ? wfc : wproj;
    f16* wT       = (z == 0) ? wqkvT : (z == 1) ? wfcT : wprojT;
    const int Ncols = (z == 0) ? 1536 : 512;
    if ((int)blockIdx.x * 32 >= Ncols) return;

    __shared__ float tile[32][33];
    const int n0 = blockIdx.x * 32, k0 = blockIdx.y * 32;
    const int tx = threadIdx.x, ty = threadIdx.y;
    for (int i = ty; i < 32; i += 8)
        tile[i][tx] = w[(long long)(k0 + i) * Ncols + n0 + tx];
    __syncthreads();
    for (int i = ty; i < 32; i += 8)
        wT[(long long)(n0 + i) * 512 + k0 + tx] = (f16)tile[tx][i];
}

// ---------------------------------------------------------------------------
// LayerNorm over last dim (512), no bias. Output fp16. One block per row.
// ---------------------------------------------------------------------------
template <typename TIN>
__global__ __launch_bounds__(256) void ln_kernel(const TIN* __restrict__ x,
                                                 const float* __restrict__ gamma,
                                                 f16* __restrict__ out) {
    const int tid = threadIdx.x;
    const long long base = (long long)blockIdx.x * ND;
    float v0, v1;
    if constexpr (sizeof(TIN) == 4) {
        const float2 t = ((const float2*)(x + base))[tid];
        v0 = t.x; v1 = t.y;
    } else {
        const f16x2 t = ((const f16x2*)(x + base))[tid];
        v0 = (float)t.x; v1 = (float)t.y;
    }

    __shared__ float red[8];
    const int wave = tid >> 6, lane = tid & 63;

    float s = v0 + v1;
#pragma unroll
    for (int o = 32; o > 0; o >>= 1) s += __shfl_down(s, o, 64);
    if (lane == 0) red[wave] = s;
    __syncthreads();
    const float mean = (red[0] + red[1] + red[2] + red[3]) * (1.f / 512.f);
    __syncthreads();

    const float d0 = v0 - mean, d1 = v1 - mean;
    float q = d0 * d0 + d1 * d1;
#pragma unroll
    for (int o = 32; o > 0; o >>= 1) q += __shfl_down(q, o, 64);
    if (lane == 0) red[wave] = q;
    __syncthreads();
    const float var = (red[0] + red[1] + red[2] + red[3]) * (1.f / 512.f);
    const float rstd = rsqrtf(var + 1e-5f);

    f16x2 o2;
    o2.x = (f16)(d0 * rstd * gamma[2 * tid]);
    o2.y = (f16)(d1 * rstd * gamma[2 * tid + 1]);
    ((f16x2*)(out + base))[tid] = o2;
}

// ---------------------------------------------------------------------------
// Masked softmax, fp16 in-place, one WAVE per row (no LDS, no barriers).
// Loads AND stores only c < round64(sz) (attn@V's BK=64 K bound; zero tail).
// ---------------------------------------------------------------------------
__global__ __launch_bounds__(256) void softmax_wave(f16* __restrict__ scores,
                                                    const int* __restrict__ sizes) {
    const int b = blockIdx.y;
    const int wave = threadIdx.x >> 6, lane = threadIdx.x & 63;
    const int row = blockIdx.x * 4 + wave;
    f16* srow = scores + ((long long)b * NN + row) * NN;
    const int sz = sizes[b];
    const int keff = (sz + 63) & ~63;
    const int cbase = lane * 16;

    float v[16];
    if (cbase < keff) {
        const f16x8 a0 = *(const f16x8*)&srow[cbase];
        const f16x8 a1 = *(const f16x8*)&srow[cbase + 8];
#pragma unroll
        for (int e = 0; e < 8; e++) { v[e] = (float)a0[e]; v[8 + e] = (float)a1[e]; }
    } else {
#pragma unroll
        for (int e = 0; e < 16; e++) v[e] = 0.f;
    }

    float m = -1e30f;
#pragma unroll
    for (int e = 0; e < 16; e++)
        if (cbase + e < sz) m = fmaxf(m, v[e]);
#pragma unroll
    for (int o = 32; o > 0; o >>= 1) m = fmaxf(m, __shfl_xor(m, o, 64));

    float s = 0.f;
#pragma unroll
    for (int e = 0; e < 16; e++) {
        v[e] = (cbase + e < sz) ? __expf(v[e] - m) : 0.f;
        s += v[e];
    }
#pragma unroll
    for (int o = 32; o > 0; o >>= 1) s += __shfl_xor(s, o, 64);
    const float inv = 1.f / s;

    if (cbase < keff) {
        f16x8 o0, o1;
#pragma unroll
        for (int e = 0; e < 8; e++) {
            o0[e] = (f16)(v[e] * inv);
            o1[e] = (f16)(v[8 + e] * inv);
        }
        *(f16x8*)&srow[cbase] = o0;
        *(f16x8*)&srow[cbase + 8] = o1;
    }
}

__device__ __forceinline__ float gelu_exact(float x) {
    return 0.5f * x * (1.f + erff(x * 0.70710678118654752f));
}

// ---------------------------------------------------------------------------
// gemm256p: 8-phase pipelined dense GEMM (see header comment).
// MODE 1: fp32 out. 2: GELU f16. 3: QKV split (qk cols <1024, vT^T >=1024).
// LDS swizzle: granule g' = g ^ (row&7); staging src col pre-swizzled,
// LDS dest linear (global_load_lds constraint).
// ---------------------------------------------------------------------------
#define SB __builtin_amdgcn_sched_barrier(0)

template <int MODE>
__global__ __launch_bounds__(512, 2) void gemm256p(
    const f16* __restrict__ A, int lda,
    const f16* __restrict__ Bt, int ldb,
    void* __restrict__ Cv, int ldc, void* __restrict__ Cv2, int K) {
    extern __shared__ __align__(16) f16 lds[];

    const int tid = threadIdx.x;
    const int wave = tid >> 6, lane = tid & 63;
    const int wr = (wave >> 2) * 128, wc = (wave & 3) * 64;
    const int lrow = lane & 15, quad = lane >> 4;

    // XCD swizzle (all users have nwg % 8 == 0: 768, 256)
    const int gx = gridDim.x;
    const int nwg = gx * (int)gridDim.y;
    const int id = blockIdx.y * gx + blockIdx.x;
    const int wid = (id & 7) * (nwg >> 3) + (id >> 3);
    const int m0 = (wid / gx) * 256;
    const int n0 = (wid % gx) * 256;

    const int NT = K >> 6;

    // staging: thread -> (row srow, swizzled granule scol) of a 64-row piece
    const int srow = tid >> 3;
    const int scol = ((tid & 7) ^ (srow & 7)) * 8;
    const f16* sA = A + (long long)(m0 + srow) * lda + scol;
    const f16* sB = Bt + (long long)(n0 + srow) * ldb + scol;

    auto stgA = [&](int ts, int r0) {
        GLOAD_LDS16(sA + (long long)r0 * lda + ts * 64,
                    lds + (ts & 1) * 32768 + r0 * 64 + tid * 8);
    };
    auto stgB = [&](int ts, int r0) {
        GLOAD_LDS16(sB + (long long)r0 * ldb + ts * 64,
                    lds + (ts & 1) * 32768 + 16384 + r0 * 64 + tid * 8);
    };

    f32x4 acc[8][4];
#pragma unroll
    for (int i = 0; i < 8; i++)
#pragma unroll
        for (int j = 0; j < 4; j++) acc[i][j] = (f32x4){0.f, 0.f, 0.f, 0.f};

    // prologue: tiles 0 and 1 fully staged (16 loads; tile0's 8 issued first)
    stgA(0, 0); stgA(0, 64); stgA(0, 128); stgA(0, 192);
    stgB(0, 0); stgB(0, 64); stgB(0, 128); stgB(0, 192);
    stgA(1, 0); stgA(1, 64); stgA(1, 128); stgA(1, 192);
    stgB(1, 0); stgB(1, 64); stgB(1, 128); stgB(1, 192);
    SB;
    asm volatile("s_waitcnt vmcnt(8)" ::: "memory");
    __builtin_amdgcn_s_barrier();
    SB;

    f16x8 aL[4][2], aH[4][2], bL[2][2], bH[2][2];

    for (int t = 0; t < NT; ++t) {
        const f16* Ab = lds + (t & 1) * 32768;
        const f16* Bb = Ab + 16384;
        const int t1 = (t + 1 < NT) ? t + 1 : t;  // clamp restages: identical bytes
        const int t2 = (t + 2 < NT) ? t + 2 : t;

        // ---------------- P1: read A-lo + B-lo; stage A-hi(t+1) ----------------
#pragma unroll
        for (int i = 0; i < 4; i++)
#pragma unroll
            for (int k2 = 0; k2 < 2; k2++)
                aL[i][k2] = *(const f16x8*)&Ab[(wr + i * 16 + lrow) * 64 +
                                               (((k2 * 4 + quad) ^ (lrow & 7)) * 8)];
#pragma unroll
        for (int j = 0; j < 2; j++)
#pragma unroll
            for (int k2 = 0; k2 < 2; k2++)
                bL[j][k2] = *(const f16x8*)&Bb[(wc + j * 16 + lrow) * 64 +
                                               (((k2 * 4 + quad) ^ (lrow & 7)) * 8)];
        stgA(t1, 64); stgA(t1, 192);
        SB;
        __builtin_amdgcn_s_barrier();
        asm volatile("s_waitcnt lgkmcnt(0)" ::: "memory");
        SB;
        __builtin_amdgcn_s_setprio(1);
#pragma unroll
        for (int i = 0; i < 4; i++)
#pragma unroll
            for (int j = 0; j < 2; j++)
#pragma unroll
                for (int k2 = 0; k2 < 2; k2++)
                    acc[i][j] = __builtin_amdgcn_mfma_f32_16x16x32_f16(aL[i][k2], bL[j][k2], acc[i][j], 0, 0, 0);
        __builtin_amdgcn_s_setprio(0);
        SB;
        __builtin_amdgcn_s_barrier();

        // ---------------- P2: read B-hi; stage A-lo(t+2) ----------------
#pragma unroll
        for (int j = 0; j < 2; j++)
#pragma unroll
            for (int k2 = 0; k2 < 2; k2++)
                bH[j][k2] = *(const f16x8*)&Bb[(wc + 32 + j * 16 + lrow) * 64 +
                                               (((k2 * 4 + quad) ^ (lrow & 7)) * 8)];
        stgA(t2, 0); stgA(t2, 128);
        SB;
        __builtin_amdgcn_s_barrier();
        asm volatile("s_waitcnt lgkmcnt(0)" ::: "memory");
        SB;
        __builtin_amdgcn_s_setprio(1);
#pragma unroll
        for (int i = 0; i < 4; i++)
#pragma unroll
            for (int j = 0; j < 2; j++)
#pragma unroll
                for (int k2 = 0; k2 < 2; k2++)
                    acc[i][2 + j] = __builtin_amdgcn_mfma_f32_16x16x32_f16(aL[i][k2], bH[j][k2], acc[i][2 + j], 0, 0, 0);
        __builtin_amdgcn_s_setprio(0);
        SB;
        __builtin_amdgcn_s_barrier();

        // ---------------- P3: read A-hi; stage B-lo(t+2) ----------------
#pragma unroll
        for (int i = 0; i < 4; i++)
#pragma unroll
            for (int k2 = 0; k2 < 2; k2++)
                aH[i][k2] = *(const f16x8*)&Ab[(wr + 64 + i * 16 + lrow) * 64 +
                                               (((k2 * 4 + quad) ^ (lrow & 7)) * 8)];
        stgB(t2, 0); stgB(t2, 64);
        SB;
        __builtin_amdgcn_s_barrier();
        asm volatile("s_waitcnt lgkmcnt(0)" ::: "memory");
        SB;
        __builtin_amdgcn_s_setprio(1);
#pragma unroll
        for (int i = 0; i < 4; i++)
#pragma unroll
            for (int j = 0; j < 2; j++)
#pragma unroll
                for (int k2 = 0; k2 < 2; k2++)
                    acc[4 + i][2 + j] = __builtin_amdgcn_mfma_f32_16x16x32_f16(aH[i][k2], bH[j][k2], acc[4 + i][2 + j], 0, 0, 0);
        __builtin_amdgcn_s_setprio(0);
        SB;
        __builtin_amdgcn_s_barrier();

        // ---------------- P4: stage B-hi(t+2); vmcnt(6) per K-tile ----------------
        stgB(t2, 128); stgB(t2, 192);
        SB;
        __builtin_amdgcn_s_barrier();
        SB;
        __builtin_amdgcn_s_setprio(1);
#pragma unroll
        for (int i = 0; i < 4; i++)
#pragma unroll
            for (int j = 0; j < 2; j++)
#pragma unroll
                for (int k2 = 0; k2 < 2; k2++)
                    acc[4 + i][j] = __builtin_amdgcn_mfma_f32_16x16x32_f16(aH[i][k2], bL[j][k2], acc[4 + i][j], 0, 0, 0);
        __builtin_amdgcn_s_setprio(0);
        SB;
        asm volatile("s_waitcnt vmcnt(6)" ::: "memory");
        __builtin_amdgcn_s_barrier();
        SB;
    }

    // epilogue: C/D layout col=lane&15, row=quad*4+reg
    const int cbase = n0 + wc + lrow;
    if constexpr (MODE == 3) {
        if (n0 >= 1024) {
            f16* vTp = (f16*)Cv2;
#pragma unroll
            for (int i = 0; i < 8; i++) {
                const int rbase = m0 + wr + i * 16 + quad * 4;
                const int bb = rbase >> 10, nrow = rbase & 1023;
                f16* vb = vTp + (long long)bb * (ND * NN) + nrow;
#pragma unroll
                for (int j = 0; j < 4; j++) {
                    const int col = cbase + j * 16 - 1024;
                    f16x4 pk;
#pragma unroll
                    for (int r = 0; r < 4; r++) pk[r] = (f16)acc[i][j][r];
                    *(f16x4*)&vb[(long long)col * NN] = pk;
                }
            }
            return;
        }
        f16* Ch = (f16*)Cv;
#pragma unroll
        for (int i = 0; i < 8; i++) {
            const int rbase = m0 + wr + i * 16 + quad * 4;
#pragma unroll
            for (int j = 0; j < 4; j++) {
                const int col = cbase + j * 16;
#pragma unroll
                for (int r = 0; r < 4; r++)
                    Ch[(long long)(rbase + r) * ldc + col] = (f16)acc[i][j][r];
            }
        }
        return;
    }
    if constexpr (MODE == 1) {
        float* Cf = (float*)Cv;
#pragma unroll
        for (int i = 0; i < 8; i++) {
            const int rbase = m0 + wr + i * 16 + quad * 4;
#pragma unroll
            for (int j = 0; j < 4; j++) {
                const int col = cbase + j * 16;
#pragma unroll
                for (int r = 0; r < 4; r++)
                    Cf[(long long)(rbase + r) * ldc + col] = acc[i][j][r];
            }
        }
    } else {  // MODE 2: GELU -> f16
        f16* Ch = (f16*)Cv;
#pragma unroll
        for (int i = 0; i < 8; i++) {
            const int rbase = m0 + wr + i * 16 + quad * 4;
#pragma unroll
            for (int j = 0; j < 4; j++) {
                const int col = cbase + j * 16;
#pragma unroll
                for (int r = 0; r < 4; r++)
                    Ch[(long long)(rbase + r) * ldc + col] = (f16)gelu_exact(acc[i][j][r]);
            }
        }
    }
}

// ---------------------------------------------------------------------------
// GEMM (128^2, 4 waves, BK=64): kept for the masked attention GEMMs.
// MODE 0: fp16*alpha. MASKN: skip block if n0 >= sizes[z]. MASKK: K bounded.
// ---------------------------------------------------------------------------
template <int MODE, int MASKN, int MASKK>
__global__ __launch_bounds__(256) void gemm_bt(
    const f16* __restrict__ A, int lda, long long strideA,
    const f16* __restrict__ Bt, int ldb, long long strideB,
    void* __restrict__ Cv, int ldc, long long strideC,
    int K, float alpha, const int* __restrict__ sizes, void* __restrict__ Cv2) {
    __shared__ __align__(16) f16 As[128 * 64];
    __shared__ __align__(16) f16 Bs[128 * 64];

    const int tid = threadIdx.x;
    const int wave = tid >> 6, lane = tid & 63;
    const int wr = (wave >> 1) * 64, wc = (wave & 1) * 64;
    const int lrow = lane & 15, quad = lane >> 4;
    const long long m0 = (long long)blockIdx.y * 128;
    const long long n0 = (long long)blockIdx.x * 128;

    if (MASKN) {
        if (n0 >= sizes[blockIdx.z]) return;
    }
    int Keff = K;
    if (MASKK) {
        const int ke = (sizes[blockIdx.z] + 63) & ~63;
        if (ke < Keff) Keff = ke;
    }

    A += (long long)blockIdx.z * strideA;
    Bt += (long long)blockIdx.z * strideB;

    f32x4 acc[4][4];
#pragma unroll
    for (int i = 0; i < 4; i++)
#pragma unroll
        for (int j = 0; j < 4; j++) acc[i][j] = (f32x4){0.f, 0.f, 0.f, 0.f};

    const f16* Ap[4];
    const f16* Bp[4];
#pragma unroll
    for (int p = 0; p < 4; p++) {
        const int s = tid + p * 256;
        const int r = s >> 3, c = ((s & 7) ^ (r & 7)) * 8;
        Ap[p] = A + (m0 + r) * lda + c;
        Bp[p] = Bt + (n0 + r) * ldb + c;
    }

    for (int k0 = 0; k0 < Keff; k0 += 64) {
        __syncthreads();
#pragma unroll
        for (int p = 0; p < 4; p++) GLOAD_LDS16(Ap[p] + k0, &As[(tid + p * 256) * 8]);
#pragma unroll
        for (int p = 0; p < 4; p++) GLOAD_LDS16(Bp[p] + k0, &Bs[(tid + p * 256) * 8]);
        __syncthreads();

#pragma unroll
        for (int h = 0; h < 2; h++) {
            const int gq = ((h * 4 + quad) ^ (lrow & 7)) * 8;
            f16x8 af[4], bf[4];
#pragma unroll
            for (int i = 0; i < 4; i++)
                af[i] = *(const f16x8*)&As[(wr + i * 16 + lrow) * 64 + gq];
#pragma unroll
            for (int j = 0; j < 4; j++)
                bf[j] = *(const f16x8*)&Bs[(wc + j * 16 + lrow) * 64 + gq];
#pragma unroll
            for (int i = 0; i < 4; i++)
#pragma unroll
                for (int j = 0; j < 4; j++)
                    acc[i][j] = __builtin_amdgcn_mfma_f32_16x16x32_f16(af[i], bf[j], acc[i][j], 0, 0, 0);
        }
    }

    f16* Ch = (f16*)Cv + (long long)blockIdx.z * strideC;
#pragma unroll
    for (int i = 0; i < 4; i++) {
        const long long rbase = m0 + wr + i * 16 + quad * 4;
#pragma unroll
        for (int j = 0; j < 4; j++) {
            const long long col = n0 + wc + j * 16 + lrow;
#pragma unroll
            for (int r = 0; r < 4; r++)
                Ch[(rbase + r) * ldc + col] = (f16)(acc[i][j][r] * alpha);
        }
    }
}

// ---------------------------------------------------------------------------
// Launch
// ---------------------------------------------------------------------------
extern "C" void kernel_launch(void* const* d_in, const int* in_sizes, int n_in,
                              void* d_out, int out_size, void* d_ws, size_t ws_size,
                              hipStream_t stream) {
    const float* x     = (const float*)d_in[0];
    const int*   sizes = (const int*)d_in[1];
    const float* g1    = (const float*)d_in[2];
    const float* wqkv  = (const float*)d_in[3];
    const float* g2    = (const float*)d_in[4];
    const float* wfc   = (const float*)d_in[5];
    const float* wproj = (const float*)d_in[6];
    float* out = (float*)d_out;
    char* ws = (char*)d_ws;

    // ---- d_ws layout (floor: 100 MiB, proven available) ----
    f16* wqkvT  = (f16*)(ws + (0ull << 20));    // 1.5 MiB  [1536][512]
    f16* wfcT   = (f16*)(ws + (2ull << 20));    // 0.5 MiB
    f16* wprojT = (f16*)(ws + (3ull << 20));    // 0.5 MiB
    f16* qk     = (f16*)(ws + (4ull << 20));    // 64 MiB [b][n][1024] (q|k)
    f16* vT     = (f16*)(ws + (68ull << 20));   // 32 MiB [b][d][n]
    f16* y      = (f16*)(ws + (4ull << 20));    // 32 MiB (qk lo, dead after scores)
    f16* ln2o   = (f16*)(ws + (36ull << 20));   // 32 MiB (qk hi, dead after scores)
    f16* gelub  = (f16*)(ws + (68ull << 20));   // 32 MiB (vT, dead after attnV)

    // ---- d_out scratch ----
    f16* h      = (f16*)d_out;   // 32 MiB, dead after QKV
    f16* scores = (f16*)d_out;   // 64 MiB (all 32 batches; h dead)

    const long long sstr = (long long)NN * NN;     // score batch stride
    const long long qstr = (long long)NN * 1024;   // qk batch stride
    const long long vstr = (long long)ND * NN;     // vT batch stride
    const long long ystr = (long long)NN * ND;     // y batch stride

    const size_t LDSB = 131072;  // 128 KiB dynamic LDS for gemm256p

    // weights -> fp16 transposed (one launch)
    transpose_cast_all<<<dim3(48, 16, 3), dim3(32, 8), 0, stream>>>(
        wqkv, wqkvT, wfc, wfcT, wproj, wprojT);

    // LN1: x -> h
    ln_kernel<float><<<NB * NN, 256, 0, stream>>>(x, g1, h);

    // QKV: q,k -> qk[b][n][1024]; v -> vT[b][d][n] (fused transpose)
    gemm256p<3><<<dim3(6, 128), 512, LDSB, stream>>>(
        h, 512, wqkvT, 512, qk, 1024, vT, 512);

    // ---- attention, single phase over all 32 batches ----
    // scores (fp16) = q @ k^T / sqrt(D); skip fully-masked column blocks
    gemm_bt<0, 1, 0><<<dim3(8, 8, 32), 256, 0, stream>>>(
        qk, 1024, qstr, qk + 512, 1024, qstr,
        scores, NN, sstr, 512, 0.044194173824159216f, sizes, nullptr);

    // masked softmax in place (wave per row), zero-fill to round64(sz)
    softmax_wave<<<dim3(NN / 4, NB), 256, 0, stream>>>(scores, sizes);

    // y = attn @ v; K bounded at round64(size)
    gemm_bt<0, 0, 1><<<dim3(4, 8, 32), 256, 0, stream>>>(
        scores, NN, sstr, vT, NN, vstr,
        y, ND, ystr, NN, 1.0f, sizes, nullptr);

    // LN2: y -> ln2o (qk hi region, dead)
    ln_kernel<f16><<<NB * NN, 256, 0, stream>>>(y, g2, ln2o);

    // FC + exact GELU: ln2o -> gelub (vT region, dead)
    gemm256p<2><<<dim3(2, 128), 512, LDSB, stream>>>(
        ln2o, 512, wfcT, 512, gelub, 512, nullptr, 512);

    // proj -> out (fp32, overwrites all of d_out; scores dead)
    gemm256p<1><<<dim3(2, 128), 512, LDSB, stream>>>(
        gelub, 512, wprojT, 512, out, 512, nullptr, 512);
}

// Round 4
// 377.692 us; speedup vs baseline: 1.0806x; 1.0806x over previous
//
#include <hip/hip_runtime.h>
#include <hip/hip_bf16.h>
#include <cmath>

// ---------------------------------------------------------------------------
// BeliefTransformerBlock: LN1 -> QKV -> masked attention -> LN2 -> FC+GELU -> proj
// B=32, N=1024, D=512.
//
// R4: ALL GEMMs on gemm256 (R2's proven 1-phase counted-vmcnt 256^2 kernel,
// generalized to runtime K-tiles + batch + MASKN/MASKK). 4-slot LDS ring,
// BK=32, vmcnt(8) per K-step (never drain-to-0 in loop), clamped tail
// restages (identical bytes -> benign). LayerNorm rewritten wave-per-row
// (no LDS, no barriers). gemm_bt retired.
//
// d_ws layout (floor 100 MiB):
//   0  wqkvT/wfcT/wprojT (4 MiB)
//   4  qk [b][n][1024] q|k (64 MiB)   -> after scores: y @4 (32), ln2o @36 (32)
//   68 vT [b][d][n] (32 MiB)          -> after attnV: gelub @68 (32)
// d_out (64 MiB): h/scoresAll scratch, finally fp32 out.
// ---------------------------------------------------------------------------

using f16 = _Float16;
typedef _Float16 f16x8 __attribute__((ext_vector_type(8)));
typedef _Float16 f16x4 __attribute__((ext_vector_type(4)));
typedef _Float16 f16x2 __attribute__((ext_vector_type(2)));
typedef float f32x4 __attribute__((ext_vector_type(4)));

#define NB 32
#define NN 1024
#define ND 512

#define GLOAD_LDS16(g, l)                                                     \
    __builtin_amdgcn_global_load_lds(                                         \
        (const __attribute__((address_space(1))) void*)(g),                   \
        (__attribute__((address_space(3))) void*)(l), 16, 0, 0)

// ---------------------------------------------------------------------------
// All three weights cast + transposed in ONE launch. z: 0=qkv 1=fc 2=proj.
// ---------------------------------------------------------------------------
__global__ void transpose_cast_all(const float* __restrict__ wqkv, f16* __restrict__ wqkvT,
                                   const float* __restrict__ wfc, f16* __restrict__ wfcT,
                                   const float* __restrict__ wproj, f16* __restrict__ wprojT) {
    const int z = blockIdx.z;
    const float* w = (z == 0) ? wqkv : (z == 1) ? wfc : wproj;
    f16* wT       = (z == 0) ? wqkvT : (z == 1) ? wfcT : wprojT;
    const int Ncols = (z == 0) ? 1536 : 512;
    if ((int)blockIdx.x * 32 >= Ncols) return;

    __shared__ float tile[32][33];
    const int n0 = blockIdx.x * 32, k0 = blockIdx.y * 32;
    const int tx = threadIdx.x, ty = threadIdx.y;
    for (int i = ty; i < 32; i += 8)
        tile[i][tx] = w[(long long)(k0 + i) * Ncols + n0 + tx];
    __syncthreads();
    for (int i = ty; i < 32; i += 8)
        wT[(long long)(n0 + i) * 512 + k0 + tx] = (f16)tile[tx][i];
}

// ---------------------------------------------------------------------------
// LayerNorm over last dim (512), no bias. One WAVE per row: no LDS, no
// barriers, 2x 6-step shfl reduction. 4 rows per 256-thread block.
// ---------------------------------------------------------------------------
template <typename TIN>
__global__ __launch_bounds__(256) void ln_wave(const TIN* __restrict__ x,
                                               const float* __restrict__ gamma,
                                               f16* __restrict__ out) {
    const int wave = threadIdx.x >> 6, lane = threadIdx.x & 63;
    const long long base = ((long long)blockIdx.x * 4 + wave) * ND;

    float v[8];
    float g[8];
    if constexpr (sizeof(TIN) == 4) {
        // lane covers elems {lane*4+e} and {256+lane*4+e}
        const float4* p = (const float4*)(x + base);
        const float4 a = p[lane], b = p[lane + 64];
        v[0] = a.x; v[1] = a.y; v[2] = a.z; v[3] = a.w;
        v[4] = b.x; v[5] = b.y; v[6] = b.z; v[7] = b.w;
        const float4* gp = (const float4*)gamma;
        const float4 ga = gp[lane], gb = gp[lane + 64];
        g[0] = ga.x; g[1] = ga.y; g[2] = ga.z; g[3] = ga.w;
        g[4] = gb.x; g[5] = gb.y; g[6] = gb.z; g[7] = gb.w;
    } else {
        // lane covers elems {lane*8+e}
        const f16x8 t = ((const f16x8*)(x + base))[lane];
#pragma unroll
        for (int e = 0; e < 8; e++) v[e] = (float)t[e];
        const float4* gp = (const float4*)gamma;
        const float4 ga = gp[2 * lane], gb = gp[2 * lane + 1];
        g[0] = ga.x; g[1] = ga.y; g[2] = ga.z; g[3] = ga.w;
        g[4] = gb.x; g[5] = gb.y; g[6] = gb.z; g[7] = gb.w;
    }

    float s = 0.f;
#pragma unroll
    for (int e = 0; e < 8; e++) s += v[e];
#pragma unroll
    for (int o = 32; o > 0; o >>= 1) s += __shfl_xor(s, o, 64);
    const float mean = s * (1.f / 512.f);

    float q = 0.f;
#pragma unroll
    for (int e = 0; e < 8; e++) {
        v[e] -= mean;
        q += v[e] * v[e];
    }
#pragma unroll
    for (int o = 32; o > 0; o >>= 1) q += __shfl_xor(q, o, 64);
    const float rstd = rsqrtf(q * (1.f / 512.f) + 1e-5f);

    if constexpr (sizeof(TIN) == 4) {
        f16x4 o0, o1;
#pragma unroll
        for (int e = 0; e < 4; e++) {
            o0[e] = (f16)(v[e] * rstd * g[e]);
            o1[e] = (f16)(v[4 + e] * rstd * g[4 + e]);
        }
        ((f16x4*)(out + base))[lane] = o0;
        ((f16x4*)(out + base))[lane + 64] = o1;
    } else {
        f16x8 o8;
#pragma unroll
        for (int e = 0; e < 8; e++) o8[e] = (f16)(v[e] * rstd * g[e]);
        ((f16x8*)(out + base))[lane] = o8;
    }
}

// ---------------------------------------------------------------------------
// Masked softmax, fp16 in-place, one WAVE per row (no LDS, no barriers).
// Loads AND stores only c < round64(sz) (attn@V's K bound; zero-filled tail).
// ---------------------------------------------------------------------------
__global__ __launch_bounds__(256) void softmax_wave(f16* __restrict__ scores,
                                                    const int* __restrict__ sizes) {
    const int b = blockIdx.y;
    const int wave = threadIdx.x >> 6, lane = threadIdx.x & 63;
    const int row = blockIdx.x * 4 + wave;
    f16* srow = scores + ((long long)b * NN + row) * NN;
    const int sz = sizes[b];
    const int keff = (sz + 63) & ~63;
    const int cbase = lane * 16;

    float v[16];
    if (cbase < keff) {
        const f16x8 a0 = *(const f16x8*)&srow[cbase];
        const f16x8 a1 = *(const f16x8*)&srow[cbase + 8];
#pragma unroll
        for (int e = 0; e < 8; e++) { v[e] = (float)a0[e]; v[8 + e] = (float)a1[e]; }
    } else {
#pragma unroll
        for (int e = 0; e < 16; e++) v[e] = 0.f;
    }

    float m = -1e30f;
#pragma unroll
    for (int e = 0; e < 16; e++)
        if (cbase + e < sz) m = fmaxf(m, v[e]);
#pragma unroll
    for (int o = 32; o > 0; o >>= 1) m = fmaxf(m, __shfl_xor(m, o, 64));

    float s = 0.f;
#pragma unroll
    for (int e = 0; e < 16; e++) {
        v[e] = (cbase + e < sz) ? __expf(v[e] - m) : 0.f;
        s += v[e];
    }
#pragma unroll
    for (int o = 32; o > 0; o >>= 1) s += __shfl_xor(s, o, 64);
    const float inv = 1.f / s;

    if (cbase < keff) {
        f16x8 o0, o1;
#pragma unroll
        for (int e = 0; e < 8; e++) {
            o0[e] = (f16)(v[e] * inv);
            o1[e] = (f16)(v[8 + e] * inv);
        }
        *(f16x8*)&srow[cbase] = o0;
        *(f16x8*)&srow[cbase + 8] = o1;
    }
}

__device__ __forceinline__ float gelu_exact(float x) {
    return 0.5f * x * (1.f + erff(x * 0.70710678118654752f));
}

// ---------------------------------------------------------------------------
// gemm256: C[M][N] = A[M][K] * Bt[N][K]^T, 256x256 tile, 8 waves (2Mx4N,
// wave-tile 128x64), BK=32, 4-slot LDS ring (128 KiB dynamic), counted
// vmcnt(8) pipeline (3 tiles in flight), one barrier per K-step, setprio
// around MFMA, per-slice XCD swizzle (slice nwg % 8 == 0 for all users).
// Runtime K-tile count; tail restages clamp to NT-1 (identical bytes).
// LDS bank swizzle: granule g' = g ^ ((row>>1)&3); gload_lds dest linear,
// SOURCE col pre-swizzled (involution).
// MODE 0: f16*alpha. 1: fp32. 2: GELU f16. 3: QKV split (qk | vT^T).
// MASKN: skip block if n0 >= sizes[z]. MASKK: K bounded at round64(sizes[z]).
// ---------------------------------------------------------------------------
#define STAGE256(t)                                                           \
    { const int ts_ = (t); f16* sl = lds + (ts_ & 3) * 16384;                 \
      GLOAD_LDS16(Ap0 + ts_ * 32, sl + tid * 8);                              \
      GLOAD_LDS16(Ap1 + ts_ * 32, sl + (tid + 512) * 8);                      \
      GLOAD_LDS16(Bp0 + ts_ * 32, sl + 8192 + tid * 8);                       \
      GLOAD_LDS16(Bp1 + ts_ * 32, sl + 8192 + (tid + 512) * 8); }

#define COMPUTE256(t)                                                         \
    { const f16* As_ = lds + ((t) & 3) * 16384;                               \
      const f16* Bs_ = As_ + 8192;                                            \
      f16x8 af[8], bf[4];                                                     \
      _Pragma("unroll") for (int i = 0; i < 8; i++)                           \
          af[i] = *(const f16x8*)&As_[(wr + i * 16 + lrow) * 32 + gq];        \
      _Pragma("unroll") for (int j = 0; j < 4; j++)                           \
          bf[j] = *(const f16x8*)&Bs_[(wc + j * 16 + lrow) * 32 + gq];        \
      __builtin_amdgcn_s_setprio(1);                                          \
      _Pragma("unroll") for (int i = 0; i < 8; i++)                           \
      _Pragma("unroll") for (int j = 0; j < 4; j++)                           \
          acc[i][j] = __builtin_amdgcn_mfma_f32_16x16x32_f16(af[i], bf[j], acc[i][j], 0, 0, 0); \
      __builtin_amdgcn_s_setprio(0); }

#define SYNC256(n)                                                            \
    __builtin_amdgcn_sched_barrier(0);                                        \
    asm volatile("s_waitcnt vmcnt(" #n ")" ::: "memory");                     \
    __builtin_amdgcn_s_barrier();                                             \
    asm volatile("" ::: "memory");

template <int MODE, int MASKN, int MASKK>
__global__ __launch_bounds__(512, 2) void gemm256(
    const f16* __restrict__ A, int lda, long long strideA,
    const f16* __restrict__ Bt, int ldb, long long strideB,
    void* __restrict__ Cv, int ldc, long long strideC,
    int K, float alpha, const int* __restrict__ sizes, void* __restrict__ Cv2) {
    extern __shared__ __align__(16) f16 lds[];

    const int tid = threadIdx.x;
    const int wave = tid >> 6, lane = tid & 63;
    const int wr = (wave >> 2) * 128, wc = (wave & 3) * 64;
    const int lrow = lane & 15, quad = lane >> 4;
    const int gq = (quad ^ ((lrow >> 1) & 3)) * 8;

    // per-slice XCD swizzle (slice nwg: 768/256/16/8 — all % 8 == 0)
    const int gx = gridDim.x;
    const int nwg = gx * (int)gridDim.y;
    const int id = blockIdx.y * gx + blockIdx.x;
    const int wid = (id & 7) * (nwg >> 3) + (id >> 3);
    const int m0 = (wid / gx) * 256;
    const int n0 = (wid % gx) * 256;

    if (MASKN) {
        if (n0 >= sizes[blockIdx.z]) return;
    }
    int Keff = K;
    if (MASKK) {
        const int ke = (sizes[blockIdx.z] + 63) & ~63;
        if (ke < Keff) Keff = ke;
    }
    const int NT = Keff >> 5;  // BK=32; NT >= 2 always (Keff >= 64)

    A += (long long)blockIdx.z * strideA;
    Bt += (long long)blockIdx.z * strideB;

    f32x4 acc[8][4];
#pragma unroll
    for (int i = 0; i < 8; i++)
#pragma unroll
        for (int j = 0; j < 4; j++) acc[i][j] = (f32x4){0.f, 0.f, 0.f, 0.f};

    // staging: 2 passes/matrix; slot s -> row=s>>2, granule g=s&3,
    // source col granule = g ^ ((row>>1)&3)  (involution; LDS dest linear)
    const int r0s = tid >> 2, g0s = tid & 3;
    const int r1s = (tid + 512) >> 2, g1s = tid & 3;
    const f16* Ap0 = A + (long long)(m0 + r0s) * lda + (g0s ^ ((r0s >> 1) & 3)) * 8;
    const f16* Ap1 = A + (long long)(m0 + r1s) * lda + (g1s ^ ((r1s >> 1) & 3)) * 8;
    const f16* Bp0 = Bt + (long long)(n0 + r0s) * ldb + (g0s ^ ((r0s >> 1) & 3)) * 8;
    const f16* Bp1 = Bt + (long long)(n0 + r1s) * ldb + (g1s ^ ((r1s >> 1) & 3)) * 8;

    // prologue: 3 K-tiles in flight (clamped for small NT)
    const int c1 = (1 < NT - 1) ? 1 : NT - 1;
    const int c2 = (2 < NT - 1) ? 2 : NT - 1;
    STAGE256(0); STAGE256(c1); STAGE256(c2);

    // main: tile t ready after vmcnt(8)+barrier; stage t+3 (clamped) into the
    // slot freed at the previous barrier. Ledger: 12 in flight, drain to 8.
    for (int t = 0; t < NT; ++t) {
        SYNC256(8);
        const int tn = (t + 3 < NT) ? t + 3 : NT - 1;  // clamp: identical bytes
        STAGE256(tn);
        COMPUTE256(t);
    }
    // drain trailing (clamped) stages before epilogue / wave exit
    __builtin_amdgcn_sched_barrier(0);
    asm volatile("s_waitcnt vmcnt(0)" ::: "memory");

    // epilogue: C/D layout col=lane&15, row=quad*4+reg
    const int cbase = n0 + wc + lrow;
    if constexpr (MODE == 3) {
        if (n0 >= 1024) {
            // V columns: store transposed into vT[b][d][n] as packed f16x4
            f16* vTp = (f16*)Cv2;
#pragma unroll
            for (int i = 0; i < 8; i++) {
                const int rbase = m0 + wr + i * 16 + quad * 4;
                const int bb = rbase >> 10, nrow = rbase & 1023;
                f16* vb = vTp + (long long)bb * (ND * NN) + nrow;
#pragma unroll
                for (int j = 0; j < 4; j++) {
                    const int col = cbase + j * 16 - 1024;
                    f16x4 pk;
#pragma unroll
                    for (int r = 0; r < 4; r++) pk[r] = (f16)acc[i][j][r];
                    *(f16x4*)&vb[(long long)col * NN] = pk;
                }
            }
            return;
        }
        f16* Ch = (f16*)Cv;
#pragma unroll
        for (int i = 0; i < 8; i++) {
            const int rbase = m0 + wr + i * 16 + quad * 4;
#pragma unroll
            for (int j = 0; j < 4; j++) {
                const int col = cbase + j * 16;
#pragma unroll
                for (int r = 0; r < 4; r++)
                    Ch[(long long)(rbase + r) * ldc + col] = (f16)acc[i][j][r];
            }
        }
        return;
    }
    if constexpr (MODE == 1) {
        float* Cf = (float*)Cv + (long long)blockIdx.z * strideC;
#pragma unroll
        for (int i = 0; i < 8; i++) {
            const int rbase = m0 + wr + i * 16 + quad * 4;
#pragma unroll
            for (int j = 0; j < 4; j++) {
                const int col = cbase + j * 16;
#pragma unroll
                for (int r = 0; r < 4; r++)
                    Cf[(long long)(rbase + r) * ldc + col] = acc[i][j][r];
            }
        }
    } else if constexpr (MODE == 2) {  // GELU -> f16
        f16* Ch = (f16*)Cv + (long long)blockIdx.z * strideC;
#pragma unroll
        for (int i = 0; i < 8; i++) {
            const int rbase = m0 + wr + i * 16 + quad * 4;
#pragma unroll
            for (int j = 0; j < 4; j++) {
                const int col = cbase + j * 16;
#pragma unroll
                for (int r = 0; r < 4; r++)
                    Ch[(long long)(rbase + r) * ldc + col] = (f16)gelu_exact(acc[i][j][r]);
            }
        }
    } else {  // MODE 0: f16 * alpha
        f16* Ch = (f16*)Cv + (long long)blockIdx.z * strideC;
#pragma unroll
        for (int i = 0; i < 8; i++) {
            const int rbase = m0 + wr + i * 16 + quad * 4;
#pragma unroll
            for (int j = 0; j < 4; j++) {
                const int col = cbase + j * 16;
#pragma unroll
                for (int r = 0; r < 4; r++)
                    Ch[(long long)(rbase + r) * ldc + col] = (f16)(acc[i][j][r] * alpha);
            }
        }
    }
}

// ---------------------------------------------------------------------------
// Launch
// ---------------------------------------------------------------------------
extern "C" void kernel_launch(void* const* d_in, const int* in_sizes, int n_in,
                              void* d_out, int out_size, void* d_ws, size_t ws_size,
                              hipStream_t stream) {
    const float* x     = (const float*)d_in[0];
    const int*   sizes = (const int*)d_in[1];
    const float* g1    = (const float*)d_in[2];
    const float* wqkv  = (const float*)d_in[3];
    const float* g2    = (const float*)d_in[4];
    const float* wfc   = (const float*)d_in[5];
    const float* wproj = (const float*)d_in[6];
    float* out = (float*)d_out;
    char* ws = (char*)d_ws;

    // ---- d_ws layout (floor: 100 MiB, proven available) ----
    f16* wqkvT  = (f16*)(ws + (0ull << 20));    // 1.5 MiB  [1536][512]
    f16* wfcT   = (f16*)(ws + (2ull << 20));    // 0.5 MiB
    f16* wprojT = (f16*)(ws + (3ull << 20));    // 0.5 MiB
    f16* qk     = (f16*)(ws + (4ull << 20));    // 64 MiB [b][n][1024] (q|k)
    f16* vT     = (f16*)(ws + (68ull << 20));   // 32 MiB [b][d][n]
    f16* y      = (f16*)(ws + (4ull << 20));    // 32 MiB (qk lo, dead after scores)
    f16* ln2o   = (f16*)(ws + (36ull << 20));   // 32 MiB (qk hi, dead after scores)
    f16* gelub  = (f16*)(ws + (68ull << 20));   // 32 MiB (vT, dead after attnV)

    // ---- d_out scratch ----
    f16* h      = (f16*)d_out;   // 32 MiB, dead after QKV
    f16* scores = (f16*)d_out;   // 64 MiB (all 32 batches; h dead)

    const long long sstr = (long long)NN * NN;     // score batch stride
    const long long qstr = (long long)NN * 1024;   // qk batch stride
    const long long vstr = (long long)ND * NN;     // vT batch stride
    const long long ystr = (long long)NN * ND;     // y batch stride

    const size_t LDSB = 131072;  // 128 KiB dynamic LDS for gemm256

    // weights -> fp16 transposed (one launch)
    transpose_cast_all<<<dim3(48, 16, 3), dim3(32, 8), 0, stream>>>(
        wqkv, wqkvT, wfc, wfcT, wproj, wprojT);

    // LN1: x -> h (wave per row)
    ln_wave<float><<<NB * NN / 4, 256, 0, stream>>>(x, g1, h);

    // QKV: q,k -> qk[b][n][1024]; v -> vT[b][d][n] (fused transpose)
    gemm256<3, 0, 0><<<dim3(6, 128, 1), 512, LDSB, stream>>>(
        h, 512, 0, wqkvT, 512, 0, qk, 1024, 0, 512, 1.0f, nullptr, vT);

    // scores (f16) = q @ k^T / sqrt(D); skip fully-masked 256-col blocks
    gemm256<0, 1, 0><<<dim3(4, 4, 32), 512, LDSB, stream>>>(
        qk, 1024, qstr, qk + 512, 1024, qstr,
        scores, NN, sstr, 512, 0.044194173824159216f, sizes, nullptr);

    // masked softmax in place (wave per row), zero-fill to round64(sz)
    softmax_wave<<<dim3(NN / 4, NB), 256, 0, stream>>>(scores, sizes);

    // y = attn @ v; K bounded at round64(size)
    gemm256<0, 0, 1><<<dim3(2, 4, 32), 512, LDSB, stream>>>(
        scores, NN, sstr, vT, NN, vstr,
        y, ND, ystr, NN, 1.0f, sizes, nullptr);

    // LN2: y -> ln2o (qk hi region, dead)
    ln_wave<f16><<<NB * NN / 4, 256, 0, stream>>>(y, g2, ln2o);

    // FC + exact GELU: ln2o -> gelub (vT region, dead)
    gemm256<2, 0, 0><<<dim3(2, 128, 1), 512, LDSB, stream>>>(
        ln2o, 512, 0, wfcT, 512, 0, gelub, 512, 0, 512, 1.0f, nullptr, nullptr);

    // proj -> out (fp32, overwrites all of d_out; scores dead)
    gemm256<1, 0, 0><<<dim3(2, 128, 1), 512, LDSB, stream>>>(
        gelub, 512, 0, wprojT, 512, 0, out, 512, 0, 512, 1.0f, nullptr, nullptr);
}